// Round 4
// baseline (160.648 us; speedup 1.0000x reference)
//
#include <hip/hip_runtime.h>

// Problem constants (fixed by the reference)
#define BATCH   128
#define C_IN    3
#define C_OUT   16
#define F4_PER_PLANE 16384             // 256*256/4
#define THREADS 1024                   // 16 waves
#define NWAVES  (THREADS / 64)
#define NBLK    (BATCH * 2)            // 2 blocks per batch -> 256 blocks = 1/CU
#define F4_HALF (F4_PER_PLANE / 2)     // 8192 float4 per plane-half
#define ITERS   (F4_HALF / THREADS)    // 8

// d_ws layout (floats):
//   [0 .. 1023]            : partial slots, slot = blockIdx.x, stride 4 floats
//   [1024 .. 1024+2047]    : per-batch ticket counters, stride 16 uints (64 B)
#define CNT_OFF 1024
#define CNT_STRIDE 16

// 256 blocks, 2 per batch: each block reduces HALF of its batch's 3 planes
// (393 KB/block -> one block per CU, balanced streaming floor). Pairwise
// combine via own-slot store + release fence + per-batch padded ticket;
// winner thread does the 3x16 matvec + bias + logsumexp. No single hot
// cache line (the R2 mistake), no dependent tail-kernel launch (the R1 gap).
__global__ __launch_bounds__(THREADS) void fused_pair(
        const float* __restrict__ x,        // (B, 3, 256, 256)
        const float* __restrict__ weight,   // (C_IN, C_OUT, 3, 3) flat
        const float* __restrict__ bias,     // (C_OUT,)
        float* __restrict__ ws,
        float* __restrict__ out) {          // (BATCH,)
    const int b    = blockIdx.x >> 1;
    const int half = blockIdx.x & 1;
    const int t    = threadIdx.x;
    const float4* xp = (const float4*)x
                     + (size_t)b * (3 * F4_PER_PLANE) + half * F4_HALF;

    // ---- streaming phase: 3 concurrent plane streams, float4 coalesced ----
    float a0 = 0.0f, a1 = 0.0f, a2 = 0.0f;
#pragma unroll
    for (int i = 0; i < ITERS; ++i) {
        float4 v0 = xp[0 * F4_PER_PLANE + i * THREADS + t];
        float4 v1 = xp[1 * F4_PER_PLANE + i * THREADS + t];
        float4 v2 = xp[2 * F4_PER_PLANE + i * THREADS + t];
        a0 += (v0.x + v0.y) + (v0.z + v0.w);
        a1 += (v1.x + v1.y) + (v1.z + v1.w);
        a2 += (v2.x + v2.y) + (v2.z + v2.w);
    }

    // ---- block reduction: wave64 shuffle + LDS ----
#pragma unroll
    for (int off = 32; off > 0; off >>= 1) {
        a0 += __shfl_down(a0, off, 64);
        a1 += __shfl_down(a1, off, 64);
        a2 += __shfl_down(a2, off, 64);
    }
    __shared__ float smem[NWAVES][3];
    const int lane = t & 63;
    const int wv   = t >> 6;
    if (lane == 0) { smem[wv][0] = a0; smem[wv][1] = a1; smem[wv][2] = a2; }
    __syncthreads();

    if (t != 0) return;

    float S0 = 0.0f, S1 = 0.0f, S2 = 0.0f;
#pragma unroll
    for (int w = 0; w < NWAVES; ++w) {
        S0 += smem[w][0]; S1 += smem[w][1]; S2 += smem[w][2];
    }

    // ---- pairwise combine: own slot + release fence + padded ticket ----
    float* slot = ws + blockIdx.x * 4;
    slot[0] = S0; slot[1] = S1; slot[2] = S2;
    __threadfence();                                   // release partials
    unsigned* cnt = (unsigned*)(ws + CNT_OFF) + b * CNT_STRIDE;
    unsigned prev = atomicAdd(cnt, 1u);
    if (prev != 1u) return;                            // loser exits

    __threadfence();                                   // acquire partner slot
    const float* pslot = ws + (blockIdx.x ^ 1) * 4;
    S0 += pslot[0]; S1 += pslot[1]; S2 += pslot[2];

    // ---- finalize: 3x16 kernel-sum matvec + bias + logsumexp, x10 ----
    const float inv_area = 1.0f / (258.0f * 258.0f);
    float m[C_OUT];
    float mmax = -1e30f;
#pragma unroll
    for (int co = 0; co < C_OUT; ++co) {
        float v = bias[co];
        float w0 = 0.0f, w1 = 0.0f, w2 = 0.0f;
#pragma unroll
        for (int k = 0; k < 9; ++k) {
            w0 += weight[(0 * C_OUT + co) * 9 + k];
            w1 += weight[(1 * C_OUT + co) * 9 + k];
            w2 += weight[(2 * C_OUT + co) * 9 + k];
        }
        v += (S0 * w0 + S1 * w1 + S2 * w2) * inv_area;
        m[co] = v;
        mmax = fmaxf(mmax, v);
    }
    float se = 0.0f;
#pragma unroll
    for (int co = 0; co < C_OUT; ++co) se += expf(m[co] - mmax);
    out[b] = 10.0f * (logf(se) + mmax);
}

extern "C" void kernel_launch(void* const* d_in, const int* in_sizes, int n_in,
                              void* d_out, int out_size, void* d_ws, size_t ws_size,
                              hipStream_t stream) {
    const float* x      = (const float*)d_in[0];
    const float* weight = (const float*)d_in[1];
    const float* bias   = (const float*)d_in[2];
    float* out = (float*)d_out;
    float* ws  = (float*)d_ws;

    // Zero only the ticket-counter region (8 KB); partial slots are
    // unconditionally overwritten so poison there is harmless.
    hipMemsetAsync(ws + CNT_OFF, 0, BATCH * CNT_STRIDE * sizeof(unsigned), stream);
    fused_pair<<<NBLK, THREADS, 0, stream>>>(x, weight, bias, ws, out);
}

// Round 5
// 158.585 us; speedup vs baseline: 1.0130x; 1.0130x over previous
//
#include <hip/hip_runtime.h>

// Problem constants (fixed by the reference)
#define BATCH   128
#define C_IN    3
#define C_OUT   16
#define F4_PER_PLANE 16384             // 256*256/4
#define THREADS 1024                   // 16 waves
#define NWAVES  (THREADS / 64)
#define NBLK    (BATCH * 2)            // 2 blocks per batch -> 256 blocks, 1/CU
#define F4_HALF (F4_PER_PLANE / 2)     // 8192 float4 per plane-half
#define ITERS   (F4_HALF / THREADS)    // 8
#define MAGIC   0x5AD0C0DEu            // != 0xAAAAAAAA workspace poison

typedef unsigned long long u64;

// 256 blocks, 2 per batch half: each block reduces HALF of its batch's 3
// planes (393 KB/block = balanced 256-CU streaming). Pair handshake uses two
// 64-bit agent-scope atomic stores (relaxed + release-tagged) and an acquire
// spin — no memset node, no ticket atomic, and critically no __threadfence()
// (which cost a full buffer_wbl2 L2 writeback per block in R2/R4). Both pair
// members compute the tiny logsumexp redundantly; half 0 writes out[b].
__global__ __launch_bounds__(THREADS) void fused_pair2(
        const float* __restrict__ x,        // (B, 3, 256, 256)
        const float* __restrict__ weight,   // (C_IN, C_OUT, 3, 3) flat
        const float* __restrict__ bias,     // (C_OUT,)
        u64* __restrict__ ws,               // slots: 8 u64 (64 B) per block
        float* __restrict__ out) {          // (BATCH,)
    const int b    = blockIdx.x >> 1;
    const int half = blockIdx.x & 1;
    const int t    = threadIdx.x;
    const float4* xp = (const float4*)x
                     + (size_t)b * (3 * F4_PER_PLANE) + half * F4_HALF;

    // ---- streaming phase: 3 concurrent plane streams, float4 coalesced ----
    float a0 = 0.0f, a1 = 0.0f, a2 = 0.0f;
#pragma unroll
    for (int i = 0; i < ITERS; ++i) {
        float4 v0 = xp[0 * F4_PER_PLANE + i * THREADS + t];
        float4 v1 = xp[1 * F4_PER_PLANE + i * THREADS + t];
        float4 v2 = xp[2 * F4_PER_PLANE + i * THREADS + t];
        a0 += (v0.x + v0.y) + (v0.z + v0.w);
        a1 += (v1.x + v1.y) + (v1.z + v1.w);
        a2 += (v2.x + v2.y) + (v2.z + v2.w);
    }

    // ---- block reduction: wave64 shuffle + LDS ----
#pragma unroll
    for (int off = 32; off > 0; off >>= 1) {
        a0 += __shfl_down(a0, off, 64);
        a1 += __shfl_down(a1, off, 64);
        a2 += __shfl_down(a2, off, 64);
    }
    __shared__ float smem[NWAVES][3];
    const int lane = t & 63;
    const int wv   = t >> 6;
    if (lane == 0) { smem[wv][0] = a0; smem[wv][1] = a1; smem[wv][2] = a2; }
    __syncthreads();

    if (t != 0) return;

    float S0 = 0.0f, S1 = 0.0f, S2 = 0.0f;
#pragma unroll
    for (int w = 0; w < NWAVES; ++w) {
        S0 += smem[w][0]; S1 += smem[w][1]; S2 += smem[w][2];
    }

    // ---- publish own partials: (S0,S1) relaxed, (S2|MAGIC) release ----
    u64* slot = ws + (size_t)blockIdx.x * 8;           // 64 B stride
    union { float f[2]; unsigned u32[2]; u64 u; } p01, p2m;
    p01.f[0] = S0; p01.f[1] = S1;
    p2m.f[0] = S2; p2m.u32[1] = MAGIC;
    __hip_atomic_store(slot + 0, p01.u, __ATOMIC_RELAXED, __HIP_MEMORY_SCOPE_AGENT);
    __hip_atomic_store(slot + 1, p2m.u, __ATOMIC_RELEASE, __HIP_MEMORY_SCOPE_AGENT);

    // ---- acquire partner partials (short spin; pair finishes ~together) ----
    u64* ps = ws + (size_t)(blockIdx.x ^ 1) * 8;
    union { float f[2]; unsigned u32[2]; u64 u; } q01, q2m;
    do {
        q2m.u = __hip_atomic_load(ps + 1, __ATOMIC_ACQUIRE, __HIP_MEMORY_SCOPE_AGENT);
    } while (q2m.u32[1] != MAGIC);
    q01.u = __hip_atomic_load(ps + 0, __ATOMIC_RELAXED, __HIP_MEMORY_SCOPE_AGENT);

    S0 += q01.f[0]; S1 += q01.f[1]; S2 += q2m.f[0];

    // ---- finalize: 3x16 kernel-sum matvec + bias + logsumexp, x10 ----
    const float inv_area = 1.0f / (258.0f * 258.0f);
    float m[C_OUT];
    float mmax = -1e30f;
#pragma unroll
    for (int co = 0; co < C_OUT; ++co) {
        float v = bias[co];
        float w0 = 0.0f, w1 = 0.0f, w2 = 0.0f;
#pragma unroll
        for (int k = 0; k < 9; ++k) {
            w0 += weight[(0 * C_OUT + co) * 9 + k];
            w1 += weight[(1 * C_OUT + co) * 9 + k];
            w2 += weight[(2 * C_OUT + co) * 9 + k];
        }
        v += (S0 * w0 + S1 * w1 + S2 * w2) * inv_area;
        m[co] = v;
        mmax = fmaxf(mmax, v);
    }
    float se = 0.0f;
#pragma unroll
    for (int co = 0; co < C_OUT; ++co) se += expf(m[co] - mmax);
    if (half == 0) out[b] = 10.0f * (logf(se) + mmax);
}

extern "C" void kernel_launch(void* const* d_in, const int* in_sizes, int n_in,
                              void* d_out, int out_size, void* d_ws, size_t ws_size,
                              hipStream_t stream) {
    const float* x      = (const float*)d_in[0];
    const float* weight = (const float*)d_in[1];
    const float* bias   = (const float*)d_in[2];
    float* out = (float*)d_out;
    u64*   ws  = (u64*)d_ws;   // 256 slots x 64 B = 16 KB; poison != MAGIC

    fused_pair2<<<NBLK, THREADS, 0, stream>>>(x, weight, bias, ws, out);
}

// Round 6
// 148.641 us; speedup vs baseline: 1.0808x; 1.0669x over previous
//
#include <hip/hip_runtime.h>

// Problem constants (fixed by the reference)
#define BATCH   128
#define C_IN    3
#define C_OUT   16
#define F4_PER_PLANE 16384             // 256*256/4
#define THREADS 1024                   // 16 waves
#define NWAVES  (THREADS / 64)
#define NBLK    (BATCH * 2)            // 2 blocks per batch -> 256 blocks, 1/CU
#define F4_HALF (F4_PER_PLANE / 2)     // 8192 float4 per plane-half
#define ITERS   (F4_HALF / THREADS)    // 8

// Main kernel: 256 blocks (exactly one per CU, 393 KB each — balanced
// streaming floor), each reduces HALF of its batch's 3 planes and writes 3
// partials with plain stores. No atomics, no fences (cross-block sync costs
// >=8 us on gfx950 — measured R2/R4/R5); visibility comes from the kernel
// boundary before the tail dispatch.
__global__ __launch_bounds__(THREADS) void main_reduce(
        const float* __restrict__ x,        // (B, 3, 256, 256)
        float* __restrict__ part) {         // 256 slots x 4 floats
    const int b    = blockIdx.x >> 1;
    const int half = blockIdx.x & 1;
    const int t    = threadIdx.x;
    const float4* xp = (const float4*)x
                     + (size_t)b * (3 * F4_PER_PLANE) + half * F4_HALF;

    float a0 = 0.0f, a1 = 0.0f, a2 = 0.0f;
#pragma unroll
    for (int i = 0; i < ITERS; ++i) {
        float4 v0 = xp[0 * F4_PER_PLANE + i * THREADS + t];
        float4 v1 = xp[1 * F4_PER_PLANE + i * THREADS + t];
        float4 v2 = xp[2 * F4_PER_PLANE + i * THREADS + t];
        a0 += (v0.x + v0.y) + (v0.z + v0.w);
        a1 += (v1.x + v1.y) + (v1.z + v1.w);
        a2 += (v2.x + v2.y) + (v2.z + v2.w);
    }

#pragma unroll
    for (int off = 32; off > 0; off >>= 1) {
        a0 += __shfl_down(a0, off, 64);
        a1 += __shfl_down(a1, off, 64);
        a2 += __shfl_down(a2, off, 64);
    }
    __shared__ float smem[NWAVES][3];
    const int lane = t & 63;
    const int wv   = t >> 6;
    if (lane == 0) { smem[wv][0] = a0; smem[wv][1] = a1; smem[wv][2] = a2; }
    __syncthreads();

    if (t == 0) {
        float S0 = 0.0f, S1 = 0.0f, S2 = 0.0f;
#pragma unroll
        for (int w = 0; w < NWAVES; ++w) {
            S0 += smem[w][0]; S1 += smem[w][1]; S2 += smem[w][2];
        }
        float* slot = part + blockIdx.x * 4;
        slot[0] = S0; slot[1] = S1; slot[2] = S2;
    }
}

// Tail kernel: one block, one thread per batch. Combine the 2 half-partials,
// fold the 3x16 kernel sums + bias + logsumexp, x10.
__global__ __launch_bounds__(BATCH) void finalize(
        const float* __restrict__ part,
        const float* __restrict__ weight,   // (C_IN, C_OUT, 3, 3) flat
        const float* __restrict__ bias,     // (C_OUT,)
        float* __restrict__ out) {          // (BATCH,)
    __shared__ float Wsum[C_IN][C_OUT];
    __shared__ float bsh[C_OUT];
    const int t = threadIdx.x;
    if (t < C_IN * C_OUT) {
        float s = 0.0f;
#pragma unroll
        for (int k = 0; k < 9; ++k) s += weight[t * 9 + k];
        Wsum[t / C_OUT][t % C_OUT] = s;
    }
    if (t < C_OUT) bsh[t] = bias[t];
    __syncthreads();

    const float* s0 = part + (t * 2 + 0) * 4;
    const float* s1 = part + (t * 2 + 1) * 4;
    const float S[C_IN] = { s0[0] + s1[0], s0[1] + s1[1], s0[2] + s1[2] };

    const float inv_area = 1.0f / (258.0f * 258.0f);
    float m[C_OUT];
    float mmax = -1e30f;
#pragma unroll
    for (int co = 0; co < C_OUT; ++co) {
        float v = (S[0] * Wsum[0][co] + S[1] * Wsum[1][co] + S[2] * Wsum[2][co])
                      * inv_area + bsh[co];
        m[co] = v;
        mmax = fmaxf(mmax, v);
    }
    float se = 0.0f;
#pragma unroll
    for (int co = 0; co < C_OUT; ++co) se += expf(m[co] - mmax);
    out[t] = 10.0f * (logf(se) + mmax);
}

extern "C" void kernel_launch(void* const* d_in, const int* in_sizes, int n_in,
                              void* d_out, int out_size, void* d_ws, size_t ws_size,
                              hipStream_t stream) {
    const float* x      = (const float*)d_in[0];
    const float* weight = (const float*)d_in[1];
    const float* bias   = (const float*)d_in[2];
    float* out  = (float*)d_out;
    float* part = (float*)d_ws;   // 256 slots x 4 floats = 4 KB

    main_reduce<<<NBLK, THREADS, 0, stream>>>(x, part);
    finalize<<<1, BATCH, 0, stream>>>(part, weight, bias, out);
}